// Round 5
// baseline (115728.857 us; speedup 1.0000x reference)
//
#include <hip/hip_runtime.h>
#include <math.h>

#define B_ 32
#define T_ 1024
#define M_ 40

// AGPR pin helpers: "a" = AGPR register class (LLVM AMDGPU inline-asm constraint).
// Writes at init pin values into the accumulator file; volatile reads in the loop
// cannot be hoisted (would explode VGPR pressure) or rematerialized.
#define AG_RD(src, dst) asm volatile("v_accvgpr_read_b32 %0, %1" : "=v"(dst) : "a"(src))

// ---------------- weight prep (transposes for coalesced access) ----------------
__global__ void prep_kernel(const float* __restrict__ W_hh, const float* __restrict__ W2,
                            const float* __restrict__ W3, const float* __restrict__ W_ih,
                            float* __restrict__ WhhT, float* __restrict__ W2t,
                            float* __restrict__ W3t, float* __restrict__ WihT4) {
  int idx = blockIdx.x * 256 + threadIdx.x;
  if (idx < 196608) {  // WhhT[k][j] = W_hh[j][k]
    int k = idx / 768, j = idx % 768;
    WhhT[idx] = W_hh[j * 256 + k];
    return;
  }
  idx -= 196608;
  if (idx < 147456) {  // W2t[tap][ci][co]
    int tap = idx >> 14, ci = (idx >> 7) & 127, co = idx & 127;
    W2t[idx] = W2[(co * 128 + ci) * 9 + tap];
    return;
  }
  idx -= 147456;
  if (idx < 147456) {  // W3t[tap][ci][co]
    int tap = idx >> 14, ci = (idx >> 7) & 127, co = idx & 127;
    W3t[idx] = W3[(co * 128 + ci) * 9 + tap];
    return;
  }
  idx -= 147456;
  if (idx < 98304) {  // WihT4[k/4][j][k%4] = W_ih[j][k] (x-part, k<128)
    int khi = idx / 3072, rem = idx % 3072, j = rem >> 2, klo = rem & 3;
    WihT4[idx] = W_ih[j * 138 + khi * 4 + klo];
  }
}

// prep2: repack the STREAMED part of W_hh for the 256-thread rnn.
// Streamed k-columns (108 of 256): k=112..127 (sb 0..3), 164..191 (sb 4..10),
// 192..255 (sb 11..26).  Layout: Wstr[(sb*3+p)*1024 + d*4 + u] = W_hh[(p*256+d)*256 + kb+u]
// so thread d reads one float4 (4 consecutive k) per (sb, plane) — 16B/lane coalesced.
__global__ void prep2_kernel(const float* __restrict__ W_hh, float* __restrict__ Wstr) {
  int idx = blockIdx.x * 256 + threadIdx.x;
  if (idx >= 82944) return;
  int sb = idx / 3072, rem = idx % 3072;
  int p = rem / 1024, r2 = rem % 1024;
  int d = r2 >> 2, u = r2 & 3;
  int kb = (sb < 4) ? (112 + sb * 4) : ((sb < 11) ? (164 + (sb - 4) * 4) : (192 + (sb - 11) * 4));
  Wstr[idx] = W_hh[(p * 256 + d) * 256 + kb + u];
}

// ---------------- fused conv1+pool5 + conv2+pool4 ----------------
// grid (T/4, B), block 256.  y2: [B][T][2][128]
__global__ __launch_bounds__(256) void conv12_kernel(
    const float* __restrict__ x, const float* __restrict__ W1, const float* __restrict__ b1,
    const float* __restrict__ W2t, const float* __restrict__ b2, float* __restrict__ y2) {
  __shared__ float xt[8 * 42];          // x rows t0-2..t0+5, mel slots -1..40
  __shared__ float y1s[6 * 128 * 12];   // y1 rows t0-1..t0+4, [row][c][mslot 0..9 (=-1..8), pad]
  const int tid = threadIdx.x;
  const int t0 = blockIdx.x * 4;
  const int b = blockIdx.y;
  for (int idx = tid; idx < 8 * 42; idx += 256) {
    int row = idx / 42, slot = idx % 42;
    int t_in = t0 - 2 + row, m = slot - 1;
    float v = 0.f;
    if (t_in >= 0 && t_in < T_ && m >= 0 && m < M_) v = x[(b * T_ + t_in) * M_ + m];
    xt[idx] = v;
  }
  __syncthreads();
  const int c = tid & 127, q = tid >> 7;
  float w1[9];
#pragma unroll
  for (int i = 0; i < 9; ++i) w1[i] = W1[c * 9 + i];
  const float b1c = b1[c];
  for (int rr = 0; rr < 3; ++rr) {
    const int r = q * 3 + rr;
    const int t_in = t0 - 1 + r;
    float* yrow = &y1s[(r * 128 + c) * 12];
    if (t_in < 0 || t_in >= T_) {
#pragma unroll
      for (int s = 0; s < 12; ++s) yrow[s] = 0.f;
    } else {
      yrow[0] = 0.f; yrow[9] = 0.f; yrow[10] = 0.f; yrow[11] = 0.f;
#pragma unroll
      for (int mo = 0; mo < 8; ++mo) {
        float mx = -1e30f;
#pragma unroll
        for (int i5 = 0; i5 < 5; ++i5) {
          const int mp = mo * 5 + i5;
          float s = b1c;
#pragma unroll
          for (int dt = 0; dt < 3; ++dt)
#pragma unroll
            for (int dm = 0; dm < 3; ++dm)
              s += xt[(r + dt) * 42 + mp + dm] * w1[dt * 3 + dm];
          mx = fmaxf(mx, s);
        }
        yrow[1 + mo] = fmaxf(mx, 0.f);  // relu after (pool of conv+b); relu monotone
      }
    }
  }
  __syncthreads();
  // conv2: thread (co, tq) computes 2 t x 8 m outputs
  const int co = c, tq = q;
  float acc[2][8];
#pragma unroll
  for (int tl = 0; tl < 2; ++tl)
#pragma unroll
    for (int mo = 0; mo < 8; ++mo) acc[tl][mo] = 0.f;
  for (int ci = 0; ci < 128; ++ci) {
    float w[9];
#pragma unroll
    for (int i = 0; i < 9; ++i) w[i] = W2t[i * 16384 + ci * 128 + co];
    float xv[4][10];
#pragma unroll
    for (int rr = 0; rr < 4; ++rr) {
      const float* p = &y1s[((2 * tq + rr) * 128 + ci) * 12];
      const float4 a = *(const float4*)p;
      const float4 bq = *(const float4*)(p + 4);
      const float2 cq = *(const float2*)(p + 8);
      xv[rr][0] = a.x; xv[rr][1] = a.y; xv[rr][2] = a.z; xv[rr][3] = a.w;
      xv[rr][4] = bq.x; xv[rr][5] = bq.y; xv[rr][6] = bq.z; xv[rr][7] = bq.w;
      xv[rr][8] = cq.x; xv[rr][9] = cq.y;
    }
#pragma unroll
    for (int dt = 0; dt < 3; ++dt)
#pragma unroll
      for (int dm = 0; dm < 3; ++dm) {
        const float wv = w[dt * 3 + dm];
#pragma unroll
        for (int tl = 0; tl < 2; ++tl)
#pragma unroll
          for (int mo = 0; mo < 8; ++mo)
            acc[tl][mo] += xv[tl + dt][mo + dm] * wv;
      }
  }
  const float b2c = b2[co];
#pragma unroll
  for (int tl = 0; tl < 2; ++tl) {
    const int t = t0 + 2 * tq + tl;
    float m0 = fmaxf(fmaxf(acc[tl][0], acc[tl][1]), fmaxf(acc[tl][2], acc[tl][3])) + b2c;
    float m1 = fmaxf(fmaxf(acc[tl][4], acc[tl][5]), fmaxf(acc[tl][6], acc[tl][7])) + b2c;
    y2[((b * T_ + t) * 2 + 0) * 128 + co] = fmaxf(m0, 0.f);
    y2[((b * T_ + t) * 2 + 1) * 128 + co] = fmaxf(m1, 0.f);
  }
}

// ---------------- conv3+pool2 -> feats [T][B][128] ----------------
__global__ __launch_bounds__(256) void conv3_kernel(
    const float* __restrict__ y2, const float* __restrict__ W3t, const float* __restrict__ b3,
    float* __restrict__ feats) {
  __shared__ float y2s[6 * 128 * 4];  // [row][ci][mslot 0..3 (=-1..2)]
  const int tid = threadIdx.x;
  const int t0 = blockIdx.x * 4;
  const int b = blockIdx.y;
  for (int idx = tid; idx < 768; idx += 256) {
    int row = idx / 128, ci = idx % 128;
    y2s[(row * 128 + ci) * 4 + 0] = 0.f;
    y2s[(row * 128 + ci) * 4 + 3] = 0.f;
  }
  for (int idx = tid; idx < 6 * 256; idx += 256) {
    int row = idx / 256, rem = idx % 256;
    int m = rem >> 7, ci = rem & 127;
    int t_in = t0 - 1 + row;
    float v = 0.f;
    if (t_in >= 0 && t_in < T_) v = y2[((b * T_ + t_in) * 2 + m) * 128 + ci];
    y2s[(row * 128 + ci) * 4 + 1 + m] = v;
  }
  __syncthreads();
  const int co = tid & 127, tq = tid >> 7;
  float acc[2][2] = {{0.f, 0.f}, {0.f, 0.f}};
  for (int ci = 0; ci < 128; ++ci) {
    float w[9];
#pragma unroll
    for (int i = 0; i < 9; ++i) w[i] = W3t[i * 16384 + ci * 128 + co];
    float4 xr[4];
#pragma unroll
    for (int rr = 0; rr < 4; ++rr)
      xr[rr] = *(const float4*)&y2s[((2 * tq + rr) * 128 + ci) * 4];
#pragma unroll
    for (int dt = 0; dt < 3; ++dt)
#pragma unroll
      for (int tl = 0; tl < 2; ++tl) {
        const float4 v = xr[tl + dt];
        acc[tl][0] += v.y * w[dt * 3 + 1] + v.z * w[dt * 3 + 2];  // m=0: taps dm=1,2
        acc[tl][1] += v.y * w[dt * 3 + 0] + v.z * w[dt * 3 + 1];  // m=1: taps dm=0,1
      }
  }
  const float b3c = b3[co];
#pragma unroll
  for (int tl = 0; tl < 2; ++tl) {
    const int t = t0 + 2 * tq + tl;
    float f = fmaxf(fmaxf(acc[tl][0], acc[tl][1]) + b3c, 0.f);
    feats[(t * B_ + b) * 128 + co] = f;
  }
}

// ---------------- gi_x = feats @ W_ih_x^T + b_ih -> [T*B][768] ----------------
__global__ __launch_bounds__(256) void gid_kernel(
    const float* __restrict__ feats, const float* __restrict__ WihT4,
    const float* __restrict__ b_ih, float* __restrict__ gi) {
  __shared__ float fs[32 * 128];
  const int tid = threadIdx.x;
  const int jb = blockIdx.x;  // 0..2
  const int rb = blockIdx.y;  // 0..1023
  const float4* src = (const float4*)(feats + rb * 32 * 128);
  float4* dst = (float4*)fs;
  for (int i = tid; i < 1024; i += 256) dst[i] = src[i];
  __syncthreads();
  const int j = jb * 256 + tid;
  float acc[32];
#pragma unroll
  for (int r = 0; r < 32; ++r) acc[r] = 0.f;
  for (int k4 = 0; k4 < 32; ++k4) {
    const float4 w4 = *(const float4*)&WihT4[(k4 * 768 + j) * 4];
#pragma unroll
    for (int r = 0; r < 32; ++r) {
      const float4 f4 = *(const float4*)&fs[r * 128 + k4 * 4];
      acc[r] += f4.x * w4.x + f4.y * w4.y + f4.z * w4.z + f4.w * w4.w;
    }
  }
  const float bj = b_ih[j];
  for (int r = 0; r < 32; ++r) gi[(rb * 32 + r) * 768 + j] = acc[r] + bj;
}

// ---------------- persistent GRU: 32 blocks x 256 threads (thread d owns dim d) ----------------
// R13 = R12 re-budgeted after R4's lesson:
//  R4 proved waves_per_eu(1,1)+256-thread DOES materialize pins (VGPR_Count=256)
//  but 336 pin + ~50 working > 256 arch VGPRs -> scratch spill, and at 1 wave/SIMD
//  scratch reloads have zero latency hiding (34-65us/step, WRITE_SIZE 34-53MB).
//  Fix: fit the pin. VGPR pin k=0..47 (144 regs, total ~210 <= 256, NO scratch);
//  AGPR pin k=48..111 (192 regs in the accumulator file via v_accvgpr_write/read
//  inline asm, "a" constraint — the compiler never uses AGPRs for plain arrays).
//  LDS k=128..163 (110.6KB), stream k=112..127,164..255 = 108 cols = 332KB/step
//  (vs R0's 672KB) via prep2's coalesced float4 layout.
//  Health check: WRITE_SIZE must be ~2.4MB (R0 level); if >>, scratch returned.
//  All fp expression orders identical to R12 (passed, absmax 0.001953125).
__global__ __attribute__((amdgpu_flat_work_group_size(256, 256), amdgpu_waves_per_eu(1, 1)))
void rnn_kernel(
    const float* __restrict__ gi, const float* __restrict__ WhhT,
    const float* __restrict__ Wstr, const float* __restrict__ W_ih,
    const float* __restrict__ b_hh, const float* __restrict__ Wf,
    const float* __restrict__ bf, const float* __restrict__ targets,
    const int* __restrict__ force_mask, float* __restrict__ out) {
  __shared__ float Wl2[36 * 768];          // k=128..163, [col][p*256+d]  110.6 KB
  __shared__ float wtf[10 * 768];          // 30 KB
  __shared__ float wfs[10 * 256];          // 10 KB
  __shared__ __align__(16) float h_s[256];
  __shared__ float tf_s[10];
  __shared__ float bf_s[10];
  const int tid = threadIdx.x;  // = hidden dim d
  const int b = blockIdx.x;
  // ---- stage LDS ----
  for (int idx = tid; idx < 36 * 768; idx += 256) {
    int col = idx / 768, j = idx % 768;
    Wl2[idx] = WhhT[(128 + col) * 768 + j];
  }
  for (int idx = tid; idx < 7680; idx += 256) {
    int cc = idx / 768, j = idx % 768;
    wtf[idx] = W_ih[j * 138 + 128 + cc];
  }
  for (int idx = tid; idx < 2560; idx += 256) wfs[idx] = Wf[idx];
  h_s[tid] = 0.f;
  if (tid < 10) { tf_s[tid] = 0.f; bf_s[tid] = bf[tid]; }
  const float bhh_r = b_hh[tid];
  const float bhh_z = b_hh[256 + tid];
  const float bhh_n = b_hh[512 + tid];
  // ---- VGPR pin k=0..47 (144 regs) ----
  float wpA[48], wpB[48], wpC[48];
#pragma unroll
  for (int kk = 0; kk < 48; ++kk) {
    wpA[kk] = WhhT[kk * 768 + tid];
    wpB[kk] = WhhT[kk * 768 + 256 + tid];
    wpC[kk] = WhhT[kk * 768 + 512 + tid];
  }
  // ---- AGPR pin k=48..111 (192 accumulator regs) ----
  float aA[64], aB[64], aC[64];
#pragma unroll
  for (int kk = 0; kk < 64; ++kk) {
    float t0 = WhhT[(48 + kk) * 768 + tid];
    float t1 = WhhT[(48 + kk) * 768 + 256 + tid];
    float t2 = WhhT[(48 + kk) * 768 + 512 + tid];
    asm volatile("v_accvgpr_write_b32 %0, %1" : "=a"(aA[kk]) : "v"(t0));
    asm volatile("v_accvgpr_write_b32 %0, %1" : "=a"(aB[kk]) : "v"(t1));
    asm volatile("v_accvgpr_write_b32 %0, %1" : "=a"(aC[kk]) : "v"(t2));
  }
  int fm_r = 0;
  float tg_r[10];
  if (tid == 0) {
    fm_r = force_mask[b];  // fm[0]
#pragma unroll
    for (int cc = 0; cc < 10; ++cc) tg_r[cc] = targets[(b * T_) * 10 + cc];
  }
  __syncthreads();

  for (int t = 0; t < T_; ++t) {
    // ---- phase A: gi loads + matvec (thread-local partials) + out(t-1) on wave 0 ----
    const int gb = (t * B_ + b) * 768 + tid;
    const float gi_r = gi[gb], gi_z = gi[gb + 256], gi_n = gi[gb + 512];
    float a0[4], a1[4], a2[4];
#pragma unroll
    for (int s = 0; s < 4; ++s) { a0[s] = 0.f; a1[s] = 0.f; a2[s] = 0.f; }
    // ks0 (k=0..63): k=0..47 VGPR pin, k=48..63 AGPR pin
#pragma unroll
    for (int g = 0; g < 12; ++g) {
      const float4 h4 = *(const float4*)&h_s[g * 4];
      a0[0] += wpA[g * 4 + 0] * h4.x + wpA[g * 4 + 1] * h4.y + wpA[g * 4 + 2] * h4.z + wpA[g * 4 + 3] * h4.w;
      a1[0] += wpB[g * 4 + 0] * h4.x + wpB[g * 4 + 1] * h4.y + wpB[g * 4 + 2] * h4.z + wpB[g * 4 + 3] * h4.w;
      a2[0] += wpC[g * 4 + 0] * h4.x + wpC[g * 4 + 1] * h4.y + wpC[g * 4 + 2] * h4.z + wpC[g * 4 + 3] * h4.w;
    }
#pragma unroll
    for (int g = 12; g < 16; ++g) {
      const float4 h4 = *(const float4*)&h_s[g * 4];
      float wa0, wa1, wa2, wa3, wb0, wb1, wb2, wb3, wc0, wc1, wc2, wc3;
      AG_RD(aA[g * 4 - 48 + 0], wa0); AG_RD(aA[g * 4 - 48 + 1], wa1);
      AG_RD(aA[g * 4 - 48 + 2], wa2); AG_RD(aA[g * 4 - 48 + 3], wa3);
      AG_RD(aB[g * 4 - 48 + 0], wb0); AG_RD(aB[g * 4 - 48 + 1], wb1);
      AG_RD(aB[g * 4 - 48 + 2], wb2); AG_RD(aB[g * 4 - 48 + 3], wb3);
      AG_RD(aC[g * 4 - 48 + 0], wc0); AG_RD(aC[g * 4 - 48 + 1], wc1);
      AG_RD(aC[g * 4 - 48 + 2], wc2); AG_RD(aC[g * 4 - 48 + 3], wc3);
      a0[0] += wa0 * h4.x + wa1 * h4.y + wa2 * h4.z + wa3 * h4.w;
      a1[0] += wb0 * h4.x + wb1 * h4.y + wb2 * h4.z + wb3 * h4.w;
      a2[0] += wc0 * h4.x + wc1 * h4.y + wc2 * h4.z + wc3 * h4.w;
    }
    // ks1 (k=64..127): k=64..111 AGPR pin (groups 0..11)...
#pragma unroll
    for (int g = 0; g < 12; ++g) {
      const float4 h4 = *(const float4*)&h_s[64 + g * 4];
      float wa0, wa1, wa2, wa3, wb0, wb1, wb2, wb3, wc0, wc1, wc2, wc3;
      AG_RD(aA[16 + g * 4 + 0], wa0); AG_RD(aA[16 + g * 4 + 1], wa1);
      AG_RD(aA[16 + g * 4 + 2], wa2); AG_RD(aA[16 + g * 4 + 3], wa3);
      AG_RD(aB[16 + g * 4 + 0], wb0); AG_RD(aB[16 + g * 4 + 1], wb1);
      AG_RD(aB[16 + g * 4 + 2], wb2); AG_RD(aB[16 + g * 4 + 3], wb3);
      AG_RD(aC[16 + g * 4 + 0], wc0); AG_RD(aC[16 + g * 4 + 1], wc1);
      AG_RD(aC[16 + g * 4 + 2], wc2); AG_RD(aC[16 + g * 4 + 3], wc3);
      a0[1] += wa0 * h4.x + wa1 * h4.y + wa2 * h4.z + wa3 * h4.w;
      a1[1] += wb0 * h4.x + wb1 * h4.y + wb2 * h4.z + wb3 * h4.w;
      a2[1] += wc0 * h4.x + wc1 * h4.y + wc2 * h4.z + wc3 * h4.w;
    }
    // ...groups 12..15 streamed (sb 0..3, k=112..127)
#pragma unroll
    for (int sb = 0; sb < 4; ++sb) {
      const float4 h4 = *(const float4*)&h_s[112 + sb * 4];
      const float4 w0 = *(const float4*)&Wstr[(sb * 3 + 0) * 1024 + tid * 4];
      const float4 w1 = *(const float4*)&Wstr[(sb * 3 + 1) * 1024 + tid * 4];
      const float4 w2 = *(const float4*)&Wstr[(sb * 3 + 2) * 1024 + tid * 4];
      a0[1] += w0.x * h4.x + w0.y * h4.y + w0.z * h4.z + w0.w * h4.w;
      a1[1] += w1.x * h4.x + w1.y * h4.y + w1.z * h4.z + w1.w * h4.w;
      a2[1] += w2.x * h4.x + w2.y * h4.y + w2.z * h4.z + w2.w * h4.w;
    }
    // ks2 (k=128..191): groups 0..8 from LDS...
#pragma unroll
    for (int g = 0; g < 9; ++g) {
      const float4 h4 = *(const float4*)&h_s[128 + g * 4];
      const float wa0 = Wl2[(g * 4 + 0) * 768 + tid];
      const float wa1 = Wl2[(g * 4 + 1) * 768 + tid];
      const float wa2 = Wl2[(g * 4 + 2) * 768 + tid];
      const float wa3 = Wl2[(g * 4 + 3) * 768 + tid];
      const float wb0 = Wl2[(g * 4 + 0) * 768 + 256 + tid];
      const float wb1 = Wl2[(g * 4 + 1) * 768 + 256 + tid];
      const float wb2 = Wl2[(g * 4 + 2) * 768 + 256 + tid];
      const float wb3 = Wl2[(g * 4 + 3) * 768 + 256 + tid];
      const float wc0 = Wl2[(g * 4 + 0) * 768 + 512 + tid];
      const float wc1 = Wl2[(g * 4 + 1) * 768 + 512 + tid];
      const float wc2 = Wl2[(g * 4 + 2) * 768 + 512 + tid];
      const float wc3 = Wl2[(g * 4 + 3) * 768 + 512 + tid];
      a0[2] += wa0 * h4.x + wa1 * h4.y + wa2 * h4.z + wa3 * h4.w;
      a1[2] += wb0 * h4.x + wb1 * h4.y + wb2 * h4.z + wb3 * h4.w;
      a2[2] += wc0 * h4.x + wc1 * h4.y + wc2 * h4.z + wc3 * h4.w;
    }
    // ...groups 9..15 streamed (sb 4..10, k=164..191)
#pragma unroll
    for (int sb = 4; sb < 11; ++sb) {
      const float4 h4 = *(const float4*)&h_s[164 + (sb - 4) * 4];
      const float4 w0 = *(const float4*)&Wstr[(sb * 3 + 0) * 1024 + tid * 4];
      const float4 w1 = *(const float4*)&Wstr[(sb * 3 + 1) * 1024 + tid * 4];
      const float4 w2 = *(const float4*)&Wstr[(sb * 3 + 2) * 1024 + tid * 4];
      a0[2] += w0.x * h4.x + w0.y * h4.y + w0.z * h4.z + w0.w * h4.w;
      a1[2] += w1.x * h4.x + w1.y * h4.y + w1.z * h4.z + w1.w * h4.w;
      a2[2] += w2.x * h4.x + w2.y * h4.y + w2.z * h4.z + w2.w * h4.w;
    }
    // ks3 (k=192..255): all streamed (sb 11..26)
#pragma unroll
    for (int sb = 11; sb < 27; ++sb) {
      const float4 h4 = *(const float4*)&h_s[192 + (sb - 11) * 4];
      const float4 w0 = *(const float4*)&Wstr[(sb * 3 + 0) * 1024 + tid * 4];
      const float4 w1 = *(const float4*)&Wstr[(sb * 3 + 1) * 1024 + tid * 4];
      const float4 w2 = *(const float4*)&Wstr[(sb * 3 + 2) * 1024 + tid * 4];
      a0[3] += w0.x * h4.x + w0.y * h4.y + w0.z * h4.z + w0.w * h4.w;
      a1[3] += w1.x * h4.x + w1.y * h4.y + w1.z * h4.z + w1.w * h4.w;
      a2[3] += w2.x * h4.x + w2.y * h4.y + w2.z * h4.z + w2.w * h4.w;
    }
    // out(t-1) + tf(t) on wave 0 (reads h_s = h(t-1); identical code to R0)
    if (t > 0 && tid < 64) {
      const float h0 = h_s[tid], h1 = h_s[tid + 64], h2 = h_s[tid + 128], h3 = h_s[tid + 192];
      float p[10];
#pragma unroll
      for (int cc = 0; cc < 10; ++cc)
        p[cc] = wfs[cc * 256 + tid] * h0 + wfs[cc * 256 + tid + 64] * h1 +
                wfs[cc * 256 + tid + 128] * h2 + wfs[cc * 256 + tid + 192] * h3;
#pragma unroll
      for (int off = 32; off > 0; off >>= 1)
#pragma unroll
        for (int cc = 0; cc < 10; ++cc) p[cc] += __shfl_xor(p[cc], off);
      if (tid == 0) {
#pragma unroll
        for (int cc = 0; cc < 10; ++cc) {
          const float o = p[cc] + bf_s[cc];
          out[(b * T_ + (t - 1)) * 10 + cc] = o;
          tf_s[cc] = (fm_r > 0) ? tg_r[cc] : (o > 0.f ? 1.f : 0.f);
        }
        fm_r = force_mask[t * B_ + b];  // prefetch step t for next iteration's out
#pragma unroll
        for (int cc = 0; cc < 10; ++cc) tg_r[cc] = targets[(b * T_ + t) * 10 + cc];
      }
    }
    __syncthreads();  // partials done (thread-local), tf_s(t) ready, h_s reads done
    // ---- phase B: gate -> h(t) (thread d owns dim d; same fp order as R0) ----
    {
      float gr = gi_r, gz = gi_z, gn0 = gi_n;
#pragma unroll
      for (int cc = 0; cc < 10; ++cc) {
        const float tfv = tf_s[cc];
        gr += wtf[cc * 768 + tid] * tfv;
        gz += wtf[cc * 768 + 256 + tid] * tfv;
        gn0 += wtf[cc * 768 + 512 + tid] * tfv;
      }
      const float ghr = bhh_r + a0[0] + a0[1] + a0[2] + a0[3];
      const float ghz = bhh_z + a1[0] + a1[1] + a1[2] + a1[3];
      const float ghn = bhh_n + a2[0] + a2[1] + a2[2] + a2[3];
      const float r = 1.f / (1.f + expf(-(gr + ghr)));
      const float z = 1.f / (1.f + expf(-(gz + ghz)));
      const float n = tanhf(gn0 + r * ghn);
      h_s[tid] = (1.f - z) * n + z * h_s[tid];
    }
    __syncthreads();  // h(t) visible for next matvec
  }
  // ---- epilogue: out(T-1) ----
  if (tid < 64) {
    const float h0 = h_s[tid], h1 = h_s[tid + 64], h2 = h_s[tid + 128], h3 = h_s[tid + 192];
    float p[10];
#pragma unroll
    for (int cc = 0; cc < 10; ++cc)
      p[cc] = wfs[cc * 256 + tid] * h0 + wfs[cc * 256 + tid + 64] * h1 +
              wfs[cc * 256 + tid + 128] * h2 + wfs[cc * 256 + tid + 192] * h3;
#pragma unroll
    for (int off = 32; off > 0; off >>= 1)
#pragma unroll
      for (int cc = 0; cc < 10; ++cc) p[cc] += __shfl_xor(p[cc], off);
    if (tid == 0) {
#pragma unroll
      for (int cc = 0; cc < 10; ++cc)
        out[(b * T_ + (T_ - 1)) * 10 + cc] = p[cc] + bf_s[cc];
    }
  }
}

extern "C" void kernel_launch(void* const* d_in, const int* in_sizes, int n_in,
                              void* d_out, int out_size, void* d_ws, size_t ws_size,
                              hipStream_t stream) {
  const float* x = (const float*)d_in[0];
  const float* targets = (const float*)d_in[1];
  const int* fmask = (const int*)d_in[2];
  const float* W1 = (const float*)d_in[3];
  const float* b1 = (const float*)d_in[4];
  const float* W2 = (const float*)d_in[5];
  const float* b2 = (const float*)d_in[6];
  const float* W3 = (const float*)d_in[7];
  const float* b3 = (const float*)d_in[8];
  const float* Wih = (const float*)d_in[9];
  const float* Whh = (const float*)d_in[10];
  const float* bih = (const float*)d_in[11];
  const float* bhh = (const float*)d_in[12];
  const float* Wf = (const float*)d_in[13];
  const float* bf = (const float*)d_in[14];
  float* out = (float*)d_out;
  float* ws = (float*)d_ws;
  // workspace layout (floats), peak 29,949,952 (~114.25 MiB).
  // y2 aliases gi (y2 dead after conv3, gi written after — stream-ordered, safe).
  // Wstr aliases feats (feats dead after gid_kernel; prep2 runs after gid).
  float* WhhT = ws;                 // 196608
  float* W2t = ws + 196608;         // 147456
  float* W3t = ws + 344064;         // 147456
  float* WihT4 = ws + 491520;       // 98304
  float* feats = ws + 589824;       // 4194304
  float* gi = ws + 4784128;         // 25165824
  float* y2 = gi;                   // 8388608 (alias)
  float* Wstr = feats;              // 82944 (alias, dead feats)

  prep_kernel<<<2304, 256, 0, stream>>>(Whh, W2, W3, Wih, WhhT, W2t, W3t, WihT4);
  conv12_kernel<<<dim3(256, 32), 256, 0, stream>>>(x, W1, b1, W2t, b2, y2);
  conv3_kernel<<<dim3(256, 32), 256, 0, stream>>>(y2, W3t, b3, feats);
  gid_kernel<<<dim3(3, 1024), 256, 0, stream>>>(feats, WihT4, bih, gi);
  prep2_kernel<<<324, 256, 0, stream>>>(Whh, Wstr);
  rnn_kernel<<<32, 256, 0, stream>>>(gi, WhhT, Wstr, Wih, bhh, Wf, bf, targets, fmask, out);
}

// Round 6
// 15788.814 us; speedup vs baseline: 7.3298x; 7.3298x over previous
//
#include <hip/hip_runtime.h>
#include <math.h>

#define B_ 32
#define T_ 1024
#define M_ 40

// ---------------- weight prep (transposes for coalesced access) ----------------
__global__ void prep_kernel(const float* __restrict__ W_hh, const float* __restrict__ W2,
                            const float* __restrict__ W3, const float* __restrict__ W_ih,
                            float* __restrict__ WhhT, float* __restrict__ W2t,
                            float* __restrict__ W3t, float* __restrict__ WihT4) {
  int idx = blockIdx.x * 256 + threadIdx.x;
  if (idx < 196608) {  // WhhT[k][j] = W_hh[j][k]
    int k = idx / 768, j = idx % 768;
    WhhT[idx] = W_hh[j * 256 + k];
    return;
  }
  idx -= 196608;
  if (idx < 147456) {  // W2t[tap][ci][co]
    int tap = idx >> 14, ci = (idx >> 7) & 127, co = idx & 127;
    W2t[idx] = W2[(co * 128 + ci) * 9 + tap];
    return;
  }
  idx -= 147456;
  if (idx < 147456) {  // W3t[tap][ci][co]
    int tap = idx >> 14, ci = (idx >> 7) & 127, co = idx & 127;
    W3t[idx] = W3[(co * 128 + ci) * 9 + tap];
    return;
  }
  idx -= 147456;
  if (idx < 98304) {  // WihT4[k/4][j][k%4] = W_ih[j][k] (x-part, k<128)
    int khi = idx / 3072, rem = idx % 3072, j = rem >> 2, klo = rem & 3;
    WihT4[idx] = W_ih[j * 138 + khi * 4 + klo];
  }
}

// prep2: repack STREAMED W_hh cols for the 512-thread rnn.
// Thread (hf,d) streams k in [128*hf+64, 128*hf+128) as 16 groups (sb) of 4 k.
// Wstr float4 index: ((hf*16+sb)*3+p)*256 + d  -> 16B/lane fully coalesced.
__global__ void prep2_kernel(const float* __restrict__ W_hh, float* __restrict__ Wstr) {
  int idx = blockIdx.x * 256 + threadIdx.x;
  if (idx >= 98304) return;
  int u = idx & 3, q = idx >> 2;
  int d = q & 255, r = q >> 8;
  int p = r % 3, g = r / 3;        // g 0..31
  int sb = g & 15, hf = g >> 4;
  int k = 128 * hf + 64 + 4 * sb + u;
  Wstr[idx] = W_hh[(p * 256 + d) * 256 + k];
}

// ---------------- fused conv1+pool5 + conv2+pool4 ----------------
// grid (T/4, B), block 256.  y2: [B][T][2][128]
__global__ __launch_bounds__(256) void conv12_kernel(
    const float* __restrict__ x, const float* __restrict__ W1, const float* __restrict__ b1,
    const float* __restrict__ W2t, const float* __restrict__ b2, float* __restrict__ y2) {
  __shared__ float xt[8 * 42];          // x rows t0-2..t0+5, mel slots -1..40
  __shared__ float y1s[6 * 128 * 12];   // y1 rows t0-1..t0+4, [row][c][mslot 0..9 (=-1..8), pad]
  const int tid = threadIdx.x;
  const int t0 = blockIdx.x * 4;
  const int b = blockIdx.y;
  for (int idx = tid; idx < 8 * 42; idx += 256) {
    int row = idx / 42, slot = idx % 42;
    int t_in = t0 - 2 + row, m = slot - 1;
    float v = 0.f;
    if (t_in >= 0 && t_in < T_ && m >= 0 && m < M_) v = x[(b * T_ + t_in) * M_ + m];
    xt[idx] = v;
  }
  __syncthreads();
  const int c = tid & 127, q = tid >> 7;
  float w1[9];
#pragma unroll
  for (int i = 0; i < 9; ++i) w1[i] = W1[c * 9 + i];
  const float b1c = b1[c];
  for (int rr = 0; rr < 3; ++rr) {
    const int r = q * 3 + rr;
    const int t_in = t0 - 1 + r;
    float* yrow = &y1s[(r * 128 + c) * 12];
    if (t_in < 0 || t_in >= T_) {
#pragma unroll
      for (int s = 0; s < 12; ++s) yrow[s] = 0.f;
    } else {
      yrow[0] = 0.f; yrow[9] = 0.f; yrow[10] = 0.f; yrow[11] = 0.f;
#pragma unroll
      for (int mo = 0; mo < 8; ++mo) {
        float mx = -1e30f;
#pragma unroll
        for (int i5 = 0; i5 < 5; ++i5) {
          const int mp = mo * 5 + i5;
          float s = b1c;
#pragma unroll
          for (int dt = 0; dt < 3; ++dt)
#pragma unroll
            for (int dm = 0; dm < 3; ++dm)
              s += xt[(r + dt) * 42 + mp + dm] * w1[dt * 3 + dm];
          mx = fmaxf(mx, s);
        }
        yrow[1 + mo] = fmaxf(mx, 0.f);  // relu after (pool of conv+b); relu monotone
      }
    }
  }
  __syncthreads();
  // conv2: thread (co, tq) computes 2 t x 8 m outputs
  const int co = c, tq = q;
  float acc[2][8];
#pragma unroll
  for (int tl = 0; tl < 2; ++tl)
#pragma unroll
    for (int mo = 0; mo < 8; ++mo) acc[tl][mo] = 0.f;
  for (int ci = 0; ci < 128; ++ci) {
    float w[9];
#pragma unroll
    for (int i = 0; i < 9; ++i) w[i] = W2t[i * 16384 + ci * 128 + co];
    float xv[4][10];
#pragma unroll
    for (int rr = 0; rr < 4; ++rr) {
      const float* p = &y1s[((2 * tq + rr) * 128 + ci) * 12];
      const float4 a = *(const float4*)p;
      const float4 bq = *(const float4*)(p + 4);
      const float2 cq = *(const float2*)(p + 8);
      xv[rr][0] = a.x; xv[rr][1] = a.y; xv[rr][2] = a.z; xv[rr][3] = a.w;
      xv[rr][4] = bq.x; xv[rr][5] = bq.y; xv[rr][6] = bq.z; xv[rr][7] = bq.w;
      xv[rr][8] = cq.x; xv[rr][9] = cq.y;
    }
#pragma unroll
    for (int dt = 0; dt < 3; ++dt)
#pragma unroll
      for (int dm = 0; dm < 3; ++dm) {
        const float wv = w[dt * 3 + dm];
#pragma unroll
        for (int tl = 0; tl < 2; ++tl)
#pragma unroll
          for (int mo = 0; mo < 8; ++mo)
            acc[tl][mo] += xv[tl + dt][mo + dm] * wv;
      }
  }
  const float b2c = b2[co];
#pragma unroll
  for (int tl = 0; tl < 2; ++tl) {
    const int t = t0 + 2 * tq + tl;
    float m0 = fmaxf(fmaxf(acc[tl][0], acc[tl][1]), fmaxf(acc[tl][2], acc[tl][3])) + b2c;
    float m1 = fmaxf(fmaxf(acc[tl][4], acc[tl][5]), fmaxf(acc[tl][6], acc[tl][7])) + b2c;
    y2[((b * T_ + t) * 2 + 0) * 128 + co] = fmaxf(m0, 0.f);
    y2[((b * T_ + t) * 2 + 1) * 128 + co] = fmaxf(m1, 0.f);
  }
}

// ---------------- conv3+pool2 -> feats [T][B][128] ----------------
__global__ __launch_bounds__(256) void conv3_kernel(
    const float* __restrict__ y2, const float* __restrict__ W3t, const float* __restrict__ b3,
    float* __restrict__ feats) {
  __shared__ float y2s[6 * 128 * 4];  // [row][ci][mslot 0..3 (=-1..2)]
  const int tid = threadIdx.x;
  const int t0 = blockIdx.x * 4;
  const int b = blockIdx.y;
  for (int idx = tid; idx < 768; idx += 256) {
    int row = idx / 128, ci = idx % 128;
    y2s[(row * 128 + ci) * 4 + 0] = 0.f;
    y2s[(row * 128 + ci) * 4 + 3] = 0.f;
  }
  for (int idx = tid; idx < 6 * 256; idx += 256) {
    int row = idx / 256, rem = idx % 256;
    int m = rem >> 7, ci = rem & 127;
    int t_in = t0 - 1 + row;
    float v = 0.f;
    if (t_in >= 0 && t_in < T_) v = y2[((b * T_ + t_in) * 2 + m) * 128 + ci];
    y2s[(row * 128 + ci) * 4 + 1 + m] = v;
  }
  __syncthreads();
  const int co = tid & 127, tq = tid >> 7;
  float acc[2][2] = {{0.f, 0.f}, {0.f, 0.f}};
  for (int ci = 0; ci < 128; ++ci) {
    float w[9];
#pragma unroll
    for (int i = 0; i < 9; ++i) w[i] = W3t[i * 16384 + ci * 128 + co];
    float4 xr[4];
#pragma unroll
    for (int rr = 0; rr < 4; ++rr)
      xr[rr] = *(const float4*)&y2s[((2 * tq + rr) * 128 + ci) * 4];
#pragma unroll
    for (int dt = 0; dt < 3; ++dt)
#pragma unroll
      for (int tl = 0; tl < 2; ++tl) {
        const float4 v = xr[tl + dt];
        acc[tl][0] += v.y * w[dt * 3 + 1] + v.z * w[dt * 3 + 2];  // m=0: taps dm=1,2
        acc[tl][1] += v.y * w[dt * 3 + 0] + v.z * w[dt * 3 + 1];  // m=1: taps dm=0,1
      }
  }
  const float b3c = b3[co];
#pragma unroll
  for (int tl = 0; tl < 2; ++tl) {
    const int t = t0 + 2 * tq + tl;
    float f = fmaxf(fmaxf(acc[tl][0], acc[tl][1]) + b3c, 0.f);
    feats[(t * B_ + b) * 128 + co] = f;
  }
}

// ---------------- gi_x = feats @ W_ih_x^T + b_ih -> [T*B][768] ----------------
__global__ __launch_bounds__(256) void gid_kernel(
    const float* __restrict__ feats, const float* __restrict__ WihT4,
    const float* __restrict__ b_ih, float* __restrict__ gi) {
  __shared__ float fs[32 * 128];
  const int tid = threadIdx.x;
  const int jb = blockIdx.x;  // 0..2
  const int rb = blockIdx.y;  // 0..1023
  const float4* src = (const float4*)(feats + rb * 32 * 128);
  float4* dst = (float4*)fs;
  for (int i = tid; i < 1024; i += 256) dst[i] = src[i];
  __syncthreads();
  const int j = jb * 256 + tid;
  float acc[32];
#pragma unroll
  for (int r = 0; r < 32; ++r) acc[r] = 0.f;
  for (int k4 = 0; k4 < 32; ++k4) {
    const float4 w4 = *(const float4*)&WihT4[(k4 * 768 + j) * 4];
#pragma unroll
    for (int r = 0; r < 32; ++r) {
      const float4 f4 = *(const float4*)&fs[r * 128 + k4 * 4];
      acc[r] += f4.x * w4.x + f4.y * w4.y + f4.z * w4.z + f4.w * w4.w;
    }
  }
  const float bj = b_ih[j];
  for (int r = 0; r < 32; ++r) gi[(rb * 32 + r) * 768 + j] = acc[r] + bj;
}

// ---------------- persistent GRU: 32 blocks x 512 threads ----------------
// R14. Thread (hf = tid>>8, d = tid&255) computes partials for gate rows
// {d, 256+d, 512+d} over k in [128*hf, 128*hf+128).  Per thread:
//   k [128hf, 128hf+48)   : VGPR pin, 144 regs (48 cols x 3 planes)
//   k [128hf+48, 128hf+64): LDS (Wl, 32 cols total = 98.3 KB)
//   k [128hf+64, 128hf+128): streamed float4 (Wstr, 384 KB/step/CU)
// Why this shape: R4 proved pins MATERIALIZE under waves_per_eu occupancy caps
// (VGPR_Count=256) and overflow SPILLS (34-65us/step); R5 proved AGPR asm is
// poison (13GB scratch).  So: plain C arrays, 144 pin + ~50 working ~ 195 <= 256
// with ~60 slack.  2 waves/SIMD (waves_per_eu(2,2), LDS 147KB -> 1 block/CU)
// doubles latency hiding vs R4's 1 wave.  Streamed bytes/step: 688KB (R3) ->
// 384KB against the per-CU VMEM port (~153 GB/s) => ~2.5-3.0us/step vs 5.33.
// Half-1 partials -> 6KB LDS; gate on half-0 threads.  FP order identical to
// R12/R4 (passed, absmax 0.001953125): gate sum bhh+(s0)+(s1)+(s2)+(s3), each
// slice ascending-k 4-wide groups.
// Spill tripwire: WRITE_SIZE must stay ~2.4MB; VGPR_Count expected ~190-230.
__global__ __attribute__((amdgpu_flat_work_group_size(512, 512), amdgpu_waves_per_eu(2, 2)))
void rnn_kernel(
    const float* __restrict__ gi, const float* __restrict__ WhhT,
    const float* __restrict__ Wstr, const float* __restrict__ W_ih,
    const float* __restrict__ b_hh, const float* __restrict__ Wf,
    const float* __restrict__ bf, const float* __restrict__ targets,
    const int* __restrict__ force_mask, float* __restrict__ out) {
  __shared__ float Wl[32 * 768];           // 98.3 KB: [col'][j]; col' 0..15 = k 48..63, 16..31 = k 176..191
  __shared__ float wtf[10 * 768];          // 30 KB
  __shared__ float wfs[10 * 256];          // 10 KB
  __shared__ float part1[6 * 256];         // 6 KB: half-1 partials [p*2+s][d]
  __shared__ __align__(16) float h_s[256];
  __shared__ float tf_s[10];
  __shared__ float bf_s[10];
  const int tid = threadIdx.x;
  const int d = tid & 255;
  const int hf = tid >> 8;
  const int b = blockIdx.x;
  // ---- stage LDS ----
  for (int idx = tid; idx < 32 * 768; idx += 512) {
    int cp = idx / 768, j = idx % 768;
    int h2 = cp >> 4, c = cp & 15;
    Wl[idx] = WhhT[(128 * h2 + 48 + c) * 768 + j];
  }
  for (int idx = tid; idx < 7680; idx += 512) {
    int cc = idx / 768, j = idx % 768;
    wtf[idx] = W_ih[j * 138 + 128 + cc];
  }
  for (int idx = tid; idx < 2560; idx += 512) wfs[idx] = Wf[idx];
  if (tid < 256) h_s[tid] = 0.f;
  if (tid < 10) { tf_s[tid] = 0.f; bf_s[tid] = bf[tid]; }
  const float bhh_r = b_hh[d];
  const float bhh_z = b_hh[256 + d];
  const float bhh_n = b_hh[512 + d];
  // ---- VGPR pin: k = 128*hf .. 128*hf+47, 3 planes = 144 regs ----
  float wpA[48], wpB[48], wpC[48];
#pragma unroll
  for (int c = 0; c < 48; ++c) {
    wpA[c] = WhhT[(128 * hf + c) * 768 + d];
    wpB[c] = WhhT[(128 * hf + c) * 768 + 256 + d];
    wpC[c] = WhhT[(128 * hf + c) * 768 + 512 + d];
  }
  int fm_r = 0;
  float tg_r[10];
  if (tid == 0) {
    fm_r = force_mask[b];  // fm[0]
#pragma unroll
    for (int cc = 0; cc < 10; ++cc) tg_r[cc] = targets[(b * T_) * 10 + cc];
  }
  const float4* W4 = (const float4*)Wstr;
  __syncthreads();

  for (int t = 0; t < T_; ++t) {
    // ---- phase A: gi loads (hf0) + matvec + out(t-1) on tid<64 ----
    float gi_r = 0.f, gi_z = 0.f, gi_n = 0.f;
    if (hf == 0) {
      const int gb = (t * B_ + b) * 768 + d;
      gi_r = gi[gb]; gi_z = gi[gb + 256]; gi_n = gi[gb + 512];
    }
    float A0[2], A1[2], A2[2];
    A0[0] = A0[1] = A1[0] = A1[1] = A2[0] = A2[1] = 0.f;
    // local slice 0 (k = 128hf .. 128hf+63): 12 reg groups + 4 LDS groups
#pragma unroll
    for (int g = 0; g < 12; ++g) {
      const float4 h4 = *(const float4*)&h_s[128 * hf + g * 4];
      A0[0] += wpA[g * 4 + 0] * h4.x + wpA[g * 4 + 1] * h4.y + wpA[g * 4 + 2] * h4.z + wpA[g * 4 + 3] * h4.w;
      A1[0] += wpB[g * 4 + 0] * h4.x + wpB[g * 4 + 1] * h4.y + wpB[g * 4 + 2] * h4.z + wpB[g * 4 + 3] * h4.w;
      A2[0] += wpC[g * 4 + 0] * h4.x + wpC[g * 4 + 1] * h4.y + wpC[g * 4 + 2] * h4.z + wpC[g * 4 + 3] * h4.w;
    }
#pragma unroll
    for (int g = 0; g < 4; ++g) {
      const float4 h4 = *(const float4*)&h_s[128 * hf + 48 + g * 4];
      const int cb = hf * 16 + g * 4;
      const float wa0 = Wl[(cb + 0) * 768 + d];
      const float wa1 = Wl[(cb + 1) * 768 + d];
      const float wa2 = Wl[(cb + 2) * 768 + d];
      const float wa3 = Wl[(cb + 3) * 768 + d];
      const float wb0 = Wl[(cb + 0) * 768 + 256 + d];
      const float wb1 = Wl[(cb + 1) * 768 + 256 + d];
      const float wb2 = Wl[(cb + 2) * 768 + 256 + d];
      const float wb3 = Wl[(cb + 3) * 768 + 256 + d];
      const float wc0 = Wl[(cb + 0) * 768 + 512 + d];
      const float wc1 = Wl[(cb + 1) * 768 + 512 + d];
      const float wc2 = Wl[(cb + 2) * 768 + 512 + d];
      const float wc3 = Wl[(cb + 3) * 768 + 512 + d];
      A0[0] += wa0 * h4.x + wa1 * h4.y + wa2 * h4.z + wa3 * h4.w;
      A1[0] += wb0 * h4.x + wb1 * h4.y + wb2 * h4.z + wb3 * h4.w;
      A2[0] += wc0 * h4.x + wc1 * h4.y + wc2 * h4.z + wc3 * h4.w;
    }
    // local slice 1 (k = 128hf+64 .. 128hf+127): 16 streamed groups
#pragma unroll
    for (int sb = 0; sb < 16; ++sb) {
      const float4 h4 = *(const float4*)&h_s[128 * hf + 64 + sb * 4];
      const float4 w0 = W4[((hf * 16 + sb) * 3 + 0) * 256 + d];
      const float4 w1 = W4[((hf * 16 + sb) * 3 + 1) * 256 + d];
      const float4 w2 = W4[((hf * 16 + sb) * 3 + 2) * 256 + d];
      A0[1] += w0.x * h4.x + w0.y * h4.y + w0.z * h4.z + w0.w * h4.w;
      A1[1] += w1.x * h4.x + w1.y * h4.y + w1.z * h4.z + w1.w * h4.w;
      A2[1] += w2.x * h4.x + w2.y * h4.y + w2.z * h4.z + w2.w * h4.w;
    }
    if (hf == 1) {
      part1[0 * 256 + d] = A0[0];
      part1[1 * 256 + d] = A0[1];
      part1[2 * 256 + d] = A1[0];
      part1[3 * 256 + d] = A1[1];
      part1[4 * 256 + d] = A2[0];
      part1[5 * 256 + d] = A2[1];
    }
    // out(t-1) + tf(t) on tid<64 (reads h_s = h(t-1); identical code to R12)
    if (t > 0 && tid < 64) {
      const float h0 = h_s[tid], h1 = h_s[tid + 64], h2 = h_s[tid + 128], h3 = h_s[tid + 192];
      float p[10];
#pragma unroll
      for (int cc = 0; cc < 10; ++cc)
        p[cc] = wfs[cc * 256 + tid] * h0 + wfs[cc * 256 + tid + 64] * h1 +
                wfs[cc * 256 + tid + 128] * h2 + wfs[cc * 256 + tid + 192] * h3;
#pragma unroll
      for (int off = 32; off > 0; off >>= 1)
#pragma unroll
        for (int cc = 0; cc < 10; ++cc) p[cc] += __shfl_xor(p[cc], off);
      if (tid == 0) {
#pragma unroll
        for (int cc = 0; cc < 10; ++cc) {
          const float o = p[cc] + bf_s[cc];
          out[(b * T_ + (t - 1)) * 10 + cc] = o;
          tf_s[cc] = (fm_r > 0) ? tg_r[cc] : (o > 0.f ? 1.f : 0.f);
        }
        fm_r = force_mask[t * B_ + b];  // prefetch step t for next iteration's out
#pragma unroll
        for (int cc = 0; cc < 10; ++cc) tg_r[cc] = targets[(b * T_ + t) * 10 + cc];
      }
    }
    __syncthreads();  // part1, tf_s(t) ready; all h_s reads done
    // ---- phase B: gate -> h(t) on hf==0 (fp order = R12: bhh + s0+s1+s2+s3) ----
    if (hf == 0) {
      float gr = gi_r, gz = gi_z, gn0 = gi_n;
#pragma unroll
      for (int cc = 0; cc < 10; ++cc) {
        const float tfv = tf_s[cc];
        gr += wtf[cc * 768 + d] * tfv;
        gz += wtf[cc * 768 + 256 + d] * tfv;
        gn0 += wtf[cc * 768 + 512 + d] * tfv;
      }
      const float ghr = bhh_r + A0[0] + A0[1] + part1[0 * 256 + d] + part1[1 * 256 + d];
      const float ghz = bhh_z + A1[0] + A1[1] + part1[2 * 256 + d] + part1[3 * 256 + d];
      const float ghn = bhh_n + A2[0] + A2[1] + part1[4 * 256 + d] + part1[5 * 256 + d];
      const float r = 1.f / (1.f + expf(-(gr + ghr)));
      const float z = 1.f / (1.f + expf(-(gz + ghz)));
      const float n = tanhf(gn0 + r * ghn);
      h_s[d] = (1.f - z) * n + z * h_s[d];
    }
    __syncthreads();  // h(t) visible for next matvec
  }
  // ---- epilogue: out(T-1) ----
  if (tid < 64) {
    const float h0 = h_s[tid], h1 = h_s[tid + 64], h2 = h_s[tid + 128], h3 = h_s[tid + 192];
    float p[10];
#pragma unroll
    for (int cc = 0; cc < 10; ++cc)
      p[cc] = wfs[cc * 256 + tid] * h0 + wfs[cc * 256 + tid + 64] * h1 +
              wfs[cc * 256 + tid + 128] * h2 + wfs[cc * 256 + tid + 192] * h3;
#pragma unroll
    for (int off = 32; off > 0; off >>= 1)
#pragma unroll
      for (int cc = 0; cc < 10; ++cc) p[cc] += __shfl_xor(p[cc], off);
    if (tid == 0) {
#pragma unroll
      for (int cc = 0; cc < 10; ++cc)
        out[(b * T_ + (T_ - 1)) * 10 + cc] = p[cc] + bf_s[cc];
    }
  }
}

extern "C" void kernel_launch(void* const* d_in, const int* in_sizes, int n_in,
                              void* d_out, int out_size, void* d_ws, size_t ws_size,
                              hipStream_t stream) {
  const float* x = (const float*)d_in[0];
  const float* targets = (const float*)d_in[1];
  const int* fmask = (const int*)d_in[2];
  const float* W1 = (const float*)d_in[3];
  const float* b1 = (const float*)d_in[4];
  const float* W2 = (const float*)d_in[5];
  const float* b2 = (const float*)d_in[6];
  const float* W3 = (const float*)d_in[7];
  const float* b3 = (const float*)d_in[8];
  const float* Wih = (const float*)d_in[9];
  const float* Whh = (const float*)d_in[10];
  const float* bih = (const float*)d_in[11];
  const float* bhh = (const float*)d_in[12];
  const float* Wf = (const float*)d_in[13];
  const float* bf = (const float*)d_in[14];
  float* out = (float*)d_out;
  float* ws = (float*)d_ws;
  // workspace layout (floats), peak 29,949,952 (~114.25 MiB).
  // y2 aliases gi (y2 dead after conv3, gi written after — stream-ordered, safe).
  // Wstr aliases feats (feats dead after gid_kernel; prep2 runs after gid).
  float* WhhT = ws;                 // 196608
  float* W2t = ws + 196608;         // 147456
  float* W3t = ws + 344064;         // 147456
  float* WihT4 = ws + 491520;       // 98304
  float* feats = ws + 589824;       // 4194304
  float* gi = ws + 4784128;         // 25165824
  float* y2 = gi;                   // 8388608 (alias)
  float* Wstr = feats;              // 98304 (alias, dead feats)

  prep_kernel<<<2304, 256, 0, stream>>>(Whh, W2, W3, Wih, WhhT, W2t, W3t, WihT4);
  conv12_kernel<<<dim3(256, 32), 256, 0, stream>>>(x, W1, b1, W2t, b2, y2);
  conv3_kernel<<<dim3(256, 32), 256, 0, stream>>>(y2, W3t, b3, feats);
  gid_kernel<<<dim3(3, 1024), 256, 0, stream>>>(feats, WihT4, bih, gi);
  prep2_kernel<<<384, 256, 0, stream>>>(Whh, Wstr);
  rnn_kernel<<<32, 512, 0, stream>>>(gi, WhhT, Wstr, Wih, bhh, Wf, bf, targets, fmask, out);
}

// Round 7
// 7249.543 us; speedup vs baseline: 15.9636x; 2.1779x over previous
//
#include <hip/hip_runtime.h>
#include <math.h>

#define B_ 32
#define T_ 1024
#define M_ 40

// ---------------- weight prep (transposes for coalesced access) ----------------
__global__ void prep_kernel(const float* __restrict__ W_hh, const float* __restrict__ W2,
                            const float* __restrict__ W3, const float* __restrict__ W_ih,
                            float* __restrict__ WhhT, float* __restrict__ W2t,
                            float* __restrict__ W3t, float* __restrict__ WihT4) {
  int idx = blockIdx.x * 256 + threadIdx.x;
  if (idx < 196608) {  // WhhT[k][j] = W_hh[j][k]
    int k = idx / 768, j = idx % 768;
    WhhT[idx] = W_hh[j * 256 + k];
    return;
  }
  idx -= 196608;
  if (idx < 147456) {  // W2t[tap][ci][co]
    int tap = idx >> 14, ci = (idx >> 7) & 127, co = idx & 127;
    W2t[idx] = W2[(co * 128 + ci) * 9 + tap];
    return;
  }
  idx -= 147456;
  if (idx < 147456) {  // W3t[tap][ci][co]
    int tap = idx >> 14, ci = (idx >> 7) & 127, co = idx & 127;
    W3t[idx] = W3[(co * 128 + ci) * 9 + tap];
    return;
  }
  idx -= 147456;
  if (idx < 98304) {  // WihT4[k/4][j][k%4] = W_ih[j][k] (x-part, k<128)
    int khi = idx / 3072, rem = idx % 3072, j = rem >> 2, klo = rem & 3;
    WihT4[idx] = W_ih[j * 138 + khi * 4 + klo];
  }
}

// ---------------- fused conv1+pool5 + conv2+pool4 ----------------
// grid (T/4, B), block 256.  y2: [B][T][2][128]
__global__ __launch_bounds__(256) void conv12_kernel(
    const float* __restrict__ x, const float* __restrict__ W1, const float* __restrict__ b1,
    const float* __restrict__ W2t, const float* __restrict__ b2, float* __restrict__ y2) {
  __shared__ float xt[8 * 42];          // x rows t0-2..t0+5, mel slots -1..40
  __shared__ float y1s[6 * 128 * 12];   // y1 rows t0-1..t0+4, [row][c][mslot 0..9 (=-1..8), pad]
  const int tid = threadIdx.x;
  const int t0 = blockIdx.x * 4;
  const int b = blockIdx.y;
  for (int idx = tid; idx < 8 * 42; idx += 256) {
    int row = idx / 42, slot = idx % 42;
    int t_in = t0 - 2 + row, m = slot - 1;
    float v = 0.f;
    if (t_in >= 0 && t_in < T_ && m >= 0 && m < M_) v = x[(b * T_ + t_in) * M_ + m];
    xt[idx] = v;
  }
  __syncthreads();
  const int c = tid & 127, q = tid >> 7;
  float w1[9];
#pragma unroll
  for (int i = 0; i < 9; ++i) w1[i] = W1[c * 9 + i];
  const float b1c = b1[c];
  for (int rr = 0; rr < 3; ++rr) {
    const int r = q * 3 + rr;
    const int t_in = t0 - 1 + r;
    float* yrow = &y1s[(r * 128 + c) * 12];
    if (t_in < 0 || t_in >= T_) {
#pragma unroll
      for (int s = 0; s < 12; ++s) yrow[s] = 0.f;
    } else {
      yrow[0] = 0.f; yrow[9] = 0.f; yrow[10] = 0.f; yrow[11] = 0.f;
#pragma unroll
      for (int mo = 0; mo < 8; ++mo) {
        float mx = -1e30f;
#pragma unroll
        for (int i5 = 0; i5 < 5; ++i5) {
          const int mp = mo * 5 + i5;
          float s = b1c;
#pragma unroll
          for (int dt = 0; dt < 3; ++dt)
#pragma unroll
            for (int dm = 0; dm < 3; ++dm)
              s += xt[(r + dt) * 42 + mp + dm] * w1[dt * 3 + dm];
          mx = fmaxf(mx, s);
        }
        yrow[1 + mo] = fmaxf(mx, 0.f);  // relu after (pool of conv+b); relu monotone
      }
    }
  }
  __syncthreads();
  // conv2: thread (co, tq) computes 2 t x 8 m outputs
  const int co = c, tq = q;
  float acc[2][8];
#pragma unroll
  for (int tl = 0; tl < 2; ++tl)
#pragma unroll
    for (int mo = 0; mo < 8; ++mo) acc[tl][mo] = 0.f;
  for (int ci = 0; ci < 128; ++ci) {
    float w[9];
#pragma unroll
    for (int i = 0; i < 9; ++i) w[i] = W2t[i * 16384 + ci * 128 + co];
    float xv[4][10];
#pragma unroll
    for (int rr = 0; rr < 4; ++rr) {
      const float* p = &y1s[((2 * tq + rr) * 128 + ci) * 12];
      const float4 a = *(const float4*)p;
      const float4 bq = *(const float4*)(p + 4);
      const float2 cq = *(const float2*)(p + 8);
      xv[rr][0] = a.x; xv[rr][1] = a.y; xv[rr][2] = a.z; xv[rr][3] = a.w;
      xv[rr][4] = bq.x; xv[rr][5] = bq.y; xv[rr][6] = bq.z; xv[rr][7] = bq.w;
      xv[rr][8] = cq.x; xv[rr][9] = cq.y;
    }
#pragma unroll
    for (int dt = 0; dt < 3; ++dt)
#pragma unroll
      for (int dm = 0; dm < 3; ++dm) {
        const float wv = w[dt * 3 + dm];
#pragma unroll
        for (int tl = 0; tl < 2; ++tl)
#pragma unroll
          for (int mo = 0; mo < 8; ++mo)
            acc[tl][mo] += xv[tl + dt][mo + dm] * wv;
      }
  }
  const float b2c = b2[co];
#pragma unroll
  for (int tl = 0; tl < 2; ++tl) {
    const int t = t0 + 2 * tq + tl;
    float m0 = fmaxf(fmaxf(acc[tl][0], acc[tl][1]), fmaxf(acc[tl][2], acc[tl][3])) + b2c;
    float m1 = fmaxf(fmaxf(acc[tl][4], acc[tl][5]), fmaxf(acc[tl][6], acc[tl][7])) + b2c;
    y2[((b * T_ + t) * 2 + 0) * 128 + co] = fmaxf(m0, 0.f);
    y2[((b * T_ + t) * 2 + 1) * 128 + co] = fmaxf(m1, 0.f);
  }
}

// ---------------- conv3+pool2 -> feats [T][B][128] ----------------
__global__ __launch_bounds__(256) void conv3_kernel(
    const float* __restrict__ y2, const float* __restrict__ W3t, const float* __restrict__ b3,
    float* __restrict__ feats) {
  __shared__ float y2s[6 * 128 * 4];  // [row][ci][mslot 0..3 (=-1..2)]
  const int tid = threadIdx.x;
  const int t0 = blockIdx.x * 4;
  const int b = blockIdx.y;
  for (int idx = tid; idx < 768; idx += 256) {
    int row = idx / 128, ci = idx % 128;
    y2s[(row * 128 + ci) * 4 + 0] = 0.f;
    y2s[(row * 128 + ci) * 4 + 3] = 0.f;
  }
  for (int idx = tid; idx < 6 * 256; idx += 256) {
    int row = idx / 256, rem = idx % 256;
    int m = rem >> 7, ci = rem & 127;
    int t_in = t0 - 1 + row;
    float v = 0.f;
    if (t_in >= 0 && t_in < T_) v = y2[((b * T_ + t_in) * 2 + m) * 128 + ci];
    y2s[(row * 128 + ci) * 4 + 1 + m] = v;
  }
  __syncthreads();
  const int co = tid & 127, tq = tid >> 7;
  float acc[2][2] = {{0.f, 0.f}, {0.f, 0.f}};
  for (int ci = 0; ci < 128; ++ci) {
    float w[9];
#pragma unroll
    for (int i = 0; i < 9; ++i) w[i] = W3t[i * 16384 + ci * 128 + co];
    float4 xr[4];
#pragma unroll
    for (int rr = 0; rr < 4; ++rr)
      xr[rr] = *(const float4*)&y2s[((2 * tq + rr) * 128 + ci) * 4];
#pragma unroll
    for (int dt = 0; dt < 3; ++dt)
#pragma unroll
      for (int tl = 0; tl < 2; ++tl) {
        const float4 v = xr[tl + dt];
        acc[tl][0] += v.y * w[dt * 3 + 1] + v.z * w[dt * 3 + 2];  // m=0: taps dm=1,2
        acc[tl][1] += v.y * w[dt * 3 + 0] + v.z * w[dt * 3 + 1];  // m=1: taps dm=0,1
      }
  }
  const float b3c = b3[co];
#pragma unroll
  for (int tl = 0; tl < 2; ++tl) {
    const int t = t0 + 2 * tq + tl;
    float f = fmaxf(fmaxf(acc[tl][0], acc[tl][1]) + b3c, 0.f);
    feats[(t * B_ + b) * 128 + co] = f;
  }
}

// ---------------- gi_x = feats @ W_ih_x^T + b_ih -> [T*B][768] ----------------
__global__ __launch_bounds__(256) void gid_kernel(
    const float* __restrict__ feats, const float* __restrict__ WihT4,
    const float* __restrict__ b_ih, float* __restrict__ gi) {
  __shared__ float fs[32 * 128];
  const int tid = threadIdx.x;
  const int jb = blockIdx.x;  // 0..2
  const int rb = blockIdx.y;  // 0..1023
  const float4* src = (const float4*)(feats + rb * 32 * 128);
  float4* dst = (float4*)fs;
  for (int i = tid; i < 1024; i += 256) dst[i] = src[i];
  __syncthreads();
  const int j = jb * 256 + tid;
  float acc[32];
#pragma unroll
  for (int r = 0; r < 32; ++r) acc[r] = 0.f;
  for (int k4 = 0; k4 < 32; ++k4) {
    const float4 w4 = *(const float4*)&WihT4[(k4 * 768 + j) * 4];
#pragma unroll
    for (int r = 0; r < 32; ++r) {
      const float4 f4 = *(const float4*)&fs[r * 128 + k4 * 4];
      acc[r] += f4.x * w4.x + f4.y * w4.y + f4.z * w4.z + f4.w * w4.w;
    }
  }
  const float bj = b_ih[j];
  for (int r = 0; r < 32; ++r) gi[(rb * 32 + r) * 768 + j] = acc[r] + bj;
}

// ---------------- persistent GRU: 32 blocks (one batch each), 768 threads ----------------
// Verified-best structure (7205.5 us total, rnn steady 5.46 us/step, absmax
// 0.001953125).  Post-R1..R6 verdict: the 96-float W "pin" below is rematerialized
// by LLVM (VGPR_Count=84) and effectively streams from L2 — every attempt to force
// residency (asm pin R1, waves_per_eu R3, 256thr/wpe(1,1) R4, AGPR asm R5,
// 512thr/wpe(2,2) R6) either changed nothing or regressed 2-20x via spill/occupancy.
// At this parallelization (1 CU/batch, the only one that survives the serial
// step dependency — cross-CU exchange costs ~5-8us/step, R2) the kernel runs at
// ~87% of the per-CU L2->CU bandwidth (672 KB/step / 5.33 us = 126 GB/s vs ~144
// measured ceiling), with LDS maxed at 155.5/160 KB.  Keep as-is.
__global__ __launch_bounds__(768, 3) void rnn_kernel(
    const float* __restrict__ gi, const float* __restrict__ WhhT,
    const float* __restrict__ W_ih, const float* __restrict__ b_hh,
    const float* __restrict__ Wf, const float* __restrict__ bf,
    const float* __restrict__ targets, const int* __restrict__ force_mask,
    float* __restrict__ out) {
  __shared__ float Wl[2 * 8 * 1536];  // [gg][fp][tid*2+par]  96.0 KB
  __shared__ float h_s[256];
  __shared__ float tf_s[16];
  __shared__ float gis[768];
  __shared__ float part[4 * 768];
  __shared__ float wtf[10 * 768];
  __shared__ float wfs[10 * 256];
  __shared__ float bhh_s[768];
  __shared__ float bf_s[16];
  const int tid = threadIdx.x;
  const int b = blockIdx.x;
  for (int idx = tid; idx < 7680; idx += 768) {
    int cc = idx / 768, j = idx % 768;
    wtf[idx] = W_ih[j * 138 + 128 + cc];
  }
  for (int idx = tid; idx < 2560; idx += 768) wfs[idx] = Wf[idx];
  bhh_s[tid] = b_hh[tid];
  if (tid < 256) h_s[tid] = 0.f;
  if (tid < 10) { tf_s[tid] = 0.f; bf_s[tid] = bf[tid]; }
  const int ks = tid / 192;   // k-slice 0..3 (wave-uniform; 192%64==0)
  const int jq = tid % 192;   // j-quad
  const float* wbase = WhhT + (ks * 64) * 768 + jq * 4;
  // pin groups 0..5 in registers
  float4 wr[6][4];
#pragma unroll
  for (int g = 0; g < 6; ++g) {
    const float* wp0 = wbase + g * 3072;
    wr[g][0] = *(const float4*)(wp0);
    wr[g][1] = *(const float4*)(wp0 + 768);
    wr[g][2] = *(const float4*)(wp0 + 1536);
    wr[g][3] = *(const float4*)(wp0 + 2304);
  }
  // fill LDS W for groups 6..7
#pragma unroll
  for (int gg = 0; gg < 2; ++gg) {
    const float* src = wbase + (6 + gg) * 3072;
#pragma unroll
    for (int fp = 0; fp < 8; ++fp) {
      const int f0 = 2 * fp, f1 = 2 * fp + 1;
      Wl[(gg * 8 + fp) * 1536 + tid * 2 + 0] = src[(f0 >> 2) * 768 + (f0 & 3)];
      Wl[(gg * 8 + fp) * 1536 + tid * 2 + 1] = src[(f1 >> 2) * 768 + (f1 & 3)];
    }
  }
  __syncthreads();

  auto matvec = [&](int tt) {
    float giv = gi[(tt * B_ + b) * 768 + tid];
    float4 a4 = make_float4(0.f, 0.f, 0.f, 0.f);
    // groups 0..5: registers
#pragma unroll
    for (int g = 0; g < 6; ++g) {
      const float4 h4 = *(const float4*)&h_s[ks * 64 + g * 4];
      a4.x += wr[g][0].x * h4.x + wr[g][1].x * h4.y + wr[g][2].x * h4.z + wr[g][3].x * h4.w;
      a4.y += wr[g][0].y * h4.x + wr[g][1].y * h4.y + wr[g][2].y * h4.z + wr[g][3].y * h4.w;
      a4.z += wr[g][0].z * h4.x + wr[g][1].z * h4.y + wr[g][2].z * h4.z + wr[g][3].z * h4.w;
      a4.w += wr[g][0].w * h4.x + wr[g][1].w * h4.y + wr[g][2].w * h4.z + wr[g][3].w * h4.w;
    }
    // groups 6..7: LDS
#pragma unroll
    for (int gg = 0; gg < 2; ++gg) {
      const float4 h4 = *(const float4*)&h_s[ks * 64 + (6 + gg) * 4];
      const float* base = &Wl[(gg * 8) * 1536 + tid * 2];
      const float2 p0 = *(const float2*)(base);
      const float2 p1 = *(const float2*)(base + 1536);
      const float2 p2 = *(const float2*)(base + 3072);
      const float2 p3 = *(const float2*)(base + 4608);
      const float2 p4 = *(const float2*)(base + 6144);
      const float2 p5 = *(const float2*)(base + 7680);
      const float2 p6 = *(const float2*)(base + 9216);
      const float2 p7 = *(const float2*)(base + 10752);
      a4.x += p0.x * h4.x + p2.x * h4.y + p4.x * h4.z + p6.x * h4.w;
      a4.y += p0.y * h4.x + p2.y * h4.y + p4.y * h4.z + p6.y * h4.w;
      a4.z += p1.x * h4.x + p3.x * h4.y + p5.x * h4.z + p7.x * h4.w;
      a4.w += p1.y * h4.x + p3.y * h4.y + p5.y * h4.z + p7.y * h4.w;
    }
    // groups 8..15: streamed from L2
    const float* wp = wbase + 8 * 3072;
#pragma unroll 2
    for (int g8 = 8; g8 < 16; ++g8) {
      const float4 w0 = *(const float4*)(wp);
      const float4 w1v = *(const float4*)(wp + 768);
      const float4 w2v = *(const float4*)(wp + 1536);
      const float4 w3v = *(const float4*)(wp + 2304);
      const float4 h4 = *(const float4*)&h_s[ks * 64 + g8 * 4];
      a4.x += w0.x * h4.x + w1v.x * h4.y + w2v.x * h4.z + w3v.x * h4.w;
      a4.y += w0.y * h4.x + w1v.y * h4.y + w2v.y * h4.z + w3v.y * h4.w;
      a4.z += w0.z * h4.x + w1v.z * h4.y + w2v.z * h4.z + w3v.z * h4.w;
      a4.w += w0.w * h4.x + w1v.w * h4.y + w2v.w * h4.z + w3v.w * h4.w;
      wp += 3072;
    }
    *(float4*)&part[ks * 768 + jq * 4] = a4;
    gis[tid] = giv;
  };

  // one-step-ahead prefetch of force_mask/targets (tid 0 only)
  int fm_r = 0;
  float tg_r[10];
  if (tid == 0) {
    fm_r = force_mask[0 * B_ + b];
#pragma unroll
    for (int cc = 0; cc < 10; ++cc) tg_r[cc] = targets[(b * T_ + 0) * 10 + cc];
  }
  matvec(0);
  __syncthreads();  // S1: part(0), gis(0) ready

  for (int t = 0; t < T_; ++t) {
    // gate phase (tid<256): gh sums + tf contribution (same fp order as R3/R8)
    if (tid < 256) {
      const int j = tid;
      float gr = gis[j], gz = gis[256 + j], gn0 = gis[512 + j];
#pragma unroll
      for (int cc = 0; cc < 10; ++cc) {
        const float tfv = tf_s[cc];
        gr += wtf[cc * 768 + j] * tfv;
        gz += wtf[cc * 768 + 256 + j] * tfv;
        gn0 += wtf[cc * 768 + 512 + j] * tfv;
      }
      float ghr = bhh_s[j] + part[j] + part[768 + j] + part[1536 + j] + part[2304 + j];
      float ghz = bhh_s[256 + j] + part[256 + j] + part[1024 + j] + part[1792 + j] + part[2560 + j];
      float ghn = bhh_s[512 + j] + part[512 + j] + part[1280 + j] + part[2048 + j] + part[2816 + j];
      const float r = 1.f / (1.f + expf(-(gr + ghr)));
      const float z = 1.f / (1.f + expf(-(gz + ghz)));
      const float n = tanhf(gn0 + r * ghn);
      h_s[j] = (1.f - z) * n + z * h_s[j];
    }
    __syncthreads();  // S2: h(t) ready
    // out(t) on wave 0 + matvec(t+1) on all waves (both only READ h_s)
    if (tid < 64) {
      const float h0 = h_s[tid], h1 = h_s[tid + 64], h2 = h_s[tid + 128], h3 = h_s[tid + 192];
      float p[10];
#pragma unroll
      for (int cc = 0; cc < 10; ++cc)
        p[cc] = wfs[cc * 256 + tid] * h0 + wfs[cc * 256 + tid + 64] * h1 +
                wfs[cc * 256 + tid + 128] * h2 + wfs[cc * 256 + tid + 192] * h3;
#pragma unroll
      for (int off = 32; off > 0; off >>= 1)
#pragma unroll
        for (int cc = 0; cc < 10; ++cc) p[cc] += __shfl_xor(p[cc], off);
      if (tid == 0) {
#pragma unroll
        for (int cc = 0; cc < 10; ++cc) {
          const float o = p[cc] + bf_s[cc];
          out[(b * T_ + t) * 10 + cc] = o;
          tf_s[cc] = (fm_r > 0) ? tg_r[cc] : (o > 0.f ? 1.f : 0.f);
        }
        if (t + 1 < T_) {  // prefetch next step's fm/targets
          fm_r = force_mask[(t + 1) * B_ + b];
#pragma unroll
          for (int cc = 0; cc < 10; ++cc) tg_r[cc] = targets[(b * T_ + t + 1) * 10 + cc];
        }
      }
    }
    if (t + 1 < T_) matvec(t + 1);
    __syncthreads();  // S1 for next iter: part/gis/tf_s ready
  }
}

extern "C" void kernel_launch(void* const* d_in, const int* in_sizes, int n_in,
                              void* d_out, int out_size, void* d_ws, size_t ws_size,
                              hipStream_t stream) {
  const float* x = (const float*)d_in[0];
  const float* targets = (const float*)d_in[1];
  const int* fmask = (const int*)d_in[2];
  const float* W1 = (const float*)d_in[3];
  const float* b1 = (const float*)d_in[4];
  const float* W2 = (const float*)d_in[5];
  const float* b2 = (const float*)d_in[6];
  const float* W3 = (const float*)d_in[7];
  const float* b3 = (const float*)d_in[8];
  const float* Wih = (const float*)d_in[9];
  const float* Whh = (const float*)d_in[10];
  const float* bih = (const float*)d_in[11];
  const float* bhh = (const float*)d_in[12];
  const float* Wf = (const float*)d_in[13];
  const float* bf = (const float*)d_in[14];
  float* out = (float*)d_out;
  float* ws = (float*)d_ws;
  // workspace layout (floats), peak 29,949,952 (~114.25 MiB).
  // y2 aliases gi (y2 dead after conv3, gi written after — stream-ordered, safe).
  float* WhhT = ws;                 // 196608
  float* W2t = ws + 196608;         // 147456
  float* W3t = ws + 344064;         // 147456
  float* WihT4 = ws + 491520;       // 98304
  float* feats = ws + 589824;       // 4194304
  float* gi = ws + 4784128;         // 25165824
  float* y2 = gi;                   // 8388608 (alias)

  prep_kernel<<<2304, 256, 0, stream>>>(Whh, W2, W3, Wih, WhhT, W2t, W3t, WihT4);
  conv12_kernel<<<dim3(256, 32), 256, 0, stream>>>(x, W1, b1, W2t, b2, y2);
  conv3_kernel<<<dim3(256, 32), 256, 0, stream>>>(y2, W3t, b3, feats);
  gid_kernel<<<dim3(3, 1024), 256, 0, stream>>>(feats, WihT4, bih, gi);
  rnn_kernel<<<32, 768, 0, stream>>>(gi, WhhT, Wih, bhh, Wf, bf, targets, fmask, out);
}